// Round 1
// baseline (416.099 us; speedup 1.0000x reference)
//
#include <hip/hip_runtime.h>

typedef _Float16 f16;
typedef _Float16 f16x8 __attribute__((ext_vector_type(8)));
typedef _Float16 f16x4 __attribute__((ext_vector_type(4)));
typedef float f32x4 __attribute__((ext_vector_type(4)));

#define BM 128
#define BN 128
#define BK 32
#define LDK 40  // +8 f16 pad -> only 2-way LDS bank aliasing (free, m136)

__device__ __forceinline__ float fast_tanh(float x) {
    // tanh(x) = 1 - 2/(e^{2x}+1); exact at +-inf, ~1e-6 rel err
    return 1.0f - 2.0f / (__expf(2.0f * x) + 1.0f);
}

__global__ __launch_bounds__(256) void f32_to_f16_k(const float* __restrict__ in,
                                                    f16* __restrict__ out, int n4) {
    int i = blockIdx.x * 256 + threadIdx.x;
    if (i >= n4) return;
    float4 v = ((const float4*)in)[i];
    f16x4 h = {(f16)v.x, (f16)v.y, (f16)v.z, (f16)v.w};
    *(f16x4*)(out + 4L * i) = h;
}

// out[C][R] = in[R][C], with f32->f16 convert
__global__ __launch_bounds__(256) void transpose_f16_k(const float* __restrict__ in,
                                                       f16* __restrict__ out, int R, int C) {
    int i = blockIdx.x * 256 + threadIdx.x;
    if (i >= R * C) return;
    int c = i / R, r = i - c * R;
    out[i] = (f16)in[r * C + c];
}

// NT GEMM: D[m][n] = sum_k A[m][k] * B[n][k], fp16 in, f32 accum.
// modes: 0 = store f16 C; 1 = tanh -> store f16 C + f16 C^T;
//        2 = store f16 C + f16 C^T; 3 = logits epilogue:
//            atomicAdd(logits[row], sum_n tanh(Sadd[row][n]+acc)*wvec[n])
__global__ __launch_bounds__(256) void gemm_nt(
    const f16* __restrict__ A, const f16* __restrict__ B,
    int lda, int ldb, int K,
    long sA, long sB,
    int mode,
    f16* __restrict__ Cout, int ldc, long sC,
    f16* __restrict__ CTout, int ldct, long sCT,
    const f16* __restrict__ Sadd, int ldsa, long sS,
    const float* __restrict__ wvec,
    float* __restrict__ logits, long sL)
{
    int z = blockIdx.z;
    const f16* Ab = A + (long)z * sA;
    const f16* Bb = B + (long)z * sB;
    int m0 = blockIdx.y * BM;
    int n0 = blockIdx.x * BN;
    int tid = threadIdx.x;
    int wave = tid >> 6, lane = tid & 63;
    int quad = lane >> 4, l16 = lane & 15;
    int wm = (wave >> 1) * 64, wn = (wave & 1) * 64;

    __shared__ f16 As[BM][LDK];
    __shared__ f16 Bs[BN][LDK];

    f32x4 zero = {0.f, 0.f, 0.f, 0.f};
    f32x4 acc[4][4];
#pragma unroll
    for (int i = 0; i < 4; i++)
#pragma unroll
        for (int j = 0; j < 4; j++) acc[i][j] = zero;

    // staging: tile is 128 rows x 32 f16 = 4 chunks of 16B per row.
    int r0 = tid >> 2;            // rows 0..63; +64 for second chunk set
    int c0 = (tid & 3) * 8;       // f16 col offset

    for (int k0 = 0; k0 < K; k0 += BK) {
        __syncthreads();
        *(f16x8*)&As[r0][c0]      = *(const f16x8*)(Ab + (long)(m0 + r0) * lda + k0 + c0);
        *(f16x8*)&As[64 + r0][c0] = *(const f16x8*)(Ab + (long)(m0 + 64 + r0) * lda + k0 + c0);
        *(f16x8*)&Bs[r0][c0]      = *(const f16x8*)(Bb + (long)(n0 + r0) * ldb + k0 + c0);
        *(f16x8*)&Bs[64 + r0][c0] = *(const f16x8*)(Bb + (long)(n0 + 64 + r0) * ldb + k0 + c0);
        __syncthreads();

        f16x8 af[4], bfr[4];
#pragma unroll
        for (int mt = 0; mt < 4; mt++)
            af[mt] = *(const f16x8*)&As[wm + mt * 16 + l16][quad * 8];
#pragma unroll
        for (int nt = 0; nt < 4; nt++)
            bfr[nt] = *(const f16x8*)&Bs[wn + nt * 16 + l16][quad * 8];
#pragma unroll
        for (int mt = 0; mt < 4; mt++)
#pragma unroll
            for (int nt = 0; nt < 4; nt++)
                acc[mt][nt] = __builtin_amdgcn_mfma_f32_16x16x32_f16(af[mt], bfr[nt], acc[mt][nt], 0, 0, 0);
    }

    int gmb = m0 + wm;
    int gnb = n0 + wn;

    if (mode == 3) {
        const f16* Sb = Sadd + (long)z * sS;
        float* lg = logits + (long)z * sL;
#pragma unroll
        for (int mt = 0; mt < 4; mt++) {
            int rowb = gmb + mt * 16 + quad * 4;
            float part[4] = {0.f, 0.f, 0.f, 0.f};
#pragma unroll
            for (int nt = 0; nt < 4; nt++) {
                int col = gnb + nt * 16 + l16;
                float w = wvec[col];
#pragma unroll
                for (int r = 0; r < 4; r++) {
                    float s = (float)Sb[(long)(rowb + r) * ldsa + col];
                    part[r] += fast_tanh(s + acc[mt][nt][r]) * w;
                }
            }
            // reduce across the 16 lanes of this quad (they hold the same rows)
#pragma unroll
            for (int off = 1; off < 16; off <<= 1) {
#pragma unroll
                for (int r = 0; r < 4; r++) part[r] += __shfl_xor(part[r], off);
            }
            if (l16 == 0) {
#pragma unroll
                for (int r = 0; r < 4; r++) atomicAdd(&lg[rowb + r], part[r]);
            }
        }
    } else {
        f16* Cb = Cout + (long)z * sC;
#pragma unroll
        for (int mt = 0; mt < 4; mt++) {
            int rowb = gmb + mt * 16 + quad * 4;
#pragma unroll
            for (int nt = 0; nt < 4; nt++) {
                int col = gnb + nt * 16 + l16;
                float v0 = acc[mt][nt][0], v1 = acc[mt][nt][1];
                float v2 = acc[mt][nt][2], v3 = acc[mt][nt][3];
                if (mode == 1) {
                    v0 = fast_tanh(v0); v1 = fast_tanh(v1);
                    v2 = fast_tanh(v2); v3 = fast_tanh(v3);
                }
                f16 h0 = (f16)v0, h1 = (f16)v1, h2 = (f16)v2, h3 = (f16)v3;
                Cb[(long)(rowb + 0) * ldc + col] = h0;
                Cb[(long)(rowb + 1) * ldc + col] = h1;
                Cb[(long)(rowb + 2) * ldc + col] = h2;
                Cb[(long)(rowb + 3) * ldc + col] = h3;
                if (mode >= 1) {
                    // transposed store: rows of a quad are contiguous along CT's fast dim
                    int bb = z + (rowb >> 9);  // z-batched (GEMM2) or M-batched (GEMM3)
                    int lr = rowb & 511;
                    f16x4 hv = {h0, h1, h2, h3};
                    *(f16x4*)(CTout + (long)bb * sCT + (long)col * ldct + lr) = hv;
                }
            }
        }
    }
}

__device__ __forceinline__ float block_reduce(float v, float* red, int tid, bool is_max) {
#pragma unroll
    for (int off = 32; off >= 1; off >>= 1) {
        float o = __shfl_xor(v, off);
        v = is_max ? fmaxf(v, o) : (v + o);
    }
    if ((tid & 63) == 0) red[tid >> 6] = v;
    __syncthreads();
    float t = red[0];
#pragma unroll
    for (int i = 1; i < 8; i++) t = is_max ? fmaxf(t, red[i]) : (t + red[i]);
    __syncthreads();
    return t;
}

// one block per (b, which): faithful masked softmax over 512 logits, then
// out[b,d] = sum_l p[l] * S[b,l,d]
__global__ __launch_bounds__(512) void softmax_gather(
    const float* __restrict__ logits_v, const float* __restrict__ logits_q,
    const int* __restrict__ mask1, const int* __restrict__ mask2,
    const float* __restrict__ s1, const float* __restrict__ s2,
    float* __restrict__ out)
{
    int b = blockIdx.x;
    int which = blockIdx.y;
    const float* lg = (which ? logits_q : logits_v) + (long)b * 512;
    const int*   mk = (which ? mask2 : mask1) + (long)b * 512;
    const float* S  = (which ? s2 : s1) + (long)b * 512 * 512;
    float* o = out + (long)which * 64 * 512 + (long)b * 512;

    int tid = threadIdx.x;
    __shared__ float p[512];
    __shared__ float red[8];

    float m = (float)mk[tid];
    float x = lg[tid] * m;
    float mx = block_reduce(x, red, tid, true);
    float e = __expf(x - mx);
    float S1 = block_reduce(e, red, tid, false);
    float r = (e / S1) * m;
    float S2 = block_reduce(r, red, tid, false);
    p[tid] = r / (S2 + 1e-13f);
    __syncthreads();

    float acc = 0.f;
#pragma unroll 8
    for (int l = 0; l < 512; l++) acc += p[l] * S[(long)l * 512 + tid];
    o[tid] = acc;
}

extern "C" void kernel_launch(void* const* d_in, const int* in_sizes, int n_in,
                              void* d_out, int out_size, void* d_ws, size_t ws_size,
                              hipStream_t stream) {
    const float* s1  = (const float*)d_in[0];
    const float* s2  = (const float*)d_in[1];
    const int* mask1 = (const int*)d_in[2];
    const int* mask2 = (const int*)d_in[3];
    const float* W   = (const float*)d_in[4];
    const float* Wv  = (const float*)d_in[5];
    const float* Wq  = (const float*)d_in[6];
    const float* whv = (const float*)d_in[7];
    const float* whq = (const float*)d_in[8];
    float* out = (float*)d_out;

    const long Bn = 64, L = 512, D = 512, Aa = 256;
    char* ws = (char*)d_ws;
    size_t off = 0;
    auto alloc = [&](size_t bytes) -> char* {
        char* p = ws + off;
        off += (bytes + 255) & ~(size_t)255;
        return p;
    };
    f16* s1b   = (f16*)alloc(Bn * L * D * 2);
    f16* s2b   = (f16*)alloc(Bn * L * D * 2);
    f16* s1W   = (f16*)alloc(Bn * L * D * 2);
    f16* Cb    = (f16*)alloc(Bn * L * L * 2);
    f16* s1Wv  = (f16*)alloc(Bn * L * Aa * 2);
    f16* s1WvT = (f16*)alloc(Bn * L * Aa * 2);
    f16* s2Wq  = (f16*)alloc(Bn * L * Aa * 2);
    f16* s2WqT = (f16*)alloc(Bn * L * Aa * 2);
    f16* WTb   = (f16*)alloc(D * D * 2);
    f16* WvTb  = (f16*)alloc(D * Aa * 2);
    f16* WqTb  = (f16*)alloc(D * Aa * 2);
    float* logv = (float*)alloc(2 * Bn * L * 4);
    float* logq = logv + Bn * L;
    f16* CTb = s1b;  // alias: s1b is dead before GEMM2 writes C^T
    if (ws_size < off) return;  // insufficient scratch -> fail visibly, no overrun

    int n4 = (int)(Bn * L * D / 4);
    f32_to_f16_k<<<dim3((n4 + 255) / 256), 256, 0, stream>>>(s1, s1b, n4);
    f32_to_f16_k<<<dim3((n4 + 255) / 256), 256, 0, stream>>>(s2, s2b, n4);
    transpose_f16_k<<<dim3((int)(D * D + 255) / 256), 256, 0, stream>>>(W, WTb, (int)D, (int)D);
    transpose_f16_k<<<dim3((int)(D * Aa + 255) / 256), 256, 0, stream>>>(Wv, WvTb, (int)D, (int)Aa);
    transpose_f16_k<<<dim3((int)(D * Aa + 255) / 256), 256, 0, stream>>>(Wq, WqTb, (int)D, (int)Aa);
    hipMemsetAsync(logv, 0, 2 * Bn * L * 4, stream);

    // GEMM1: s1W = s1 @ W      [32768 x 512] x [512 x 512]
    gemm_nt<<<dim3((int)(D / BN), (int)(Bn * L / BM), 1), 256, 0, stream>>>(
        s1b, WTb, (int)D, (int)D, (int)D, 0, 0,
        0, s1W, (int)D, 0,
        nullptr, 0, 0, nullptr, 0, 0, nullptr, nullptr, 0);

    // GEMM3a: s1Wv(+T) = s1 @ Wv   [32768 x 256]
    gemm_nt<<<dim3((int)(Aa / BN), (int)(Bn * L / BM), 1), 256, 0, stream>>>(
        s1b, WvTb, (int)D, (int)D, (int)D, 0, 0,
        2, s1Wv, (int)Aa, 0,
        s1WvT, (int)L, L * Aa, nullptr, 0, 0, nullptr, nullptr, 0);

    // GEMM3b: s2Wq(+T) = s2 @ Wq
    gemm_nt<<<dim3((int)(Aa / BN), (int)(Bn * L / BM), 1), 256, 0, stream>>>(
        s2b, WqTb, (int)D, (int)D, (int)D, 0, 0,
        2, s2Wq, (int)Aa, 0,
        s2WqT, (int)L, L * Aa, nullptr, 0, 0, nullptr, nullptr, 0);

    // GEMM2 (batched): C = tanh(s1W @ s2^T), also emits C^T
    gemm_nt<<<dim3((int)(L / BN), (int)(L / BM), (int)Bn), 256, 0, stream>>>(
        s1W, s2b, (int)D, (int)D, (int)D, L * D, L * D,
        1, Cb, (int)L, L * L,
        CTb, (int)L, L * L, nullptr, 0, 0, nullptr, nullptr, 0);

    // GEMM4a (batched): logits_v[l] += sum_a tanh(s1Wv[l,a] + (C @ s2Wq)[l,a]) * whv[a]
    gemm_nt<<<dim3((int)(Aa / BN), (int)(L / BM), (int)Bn), 256, 0, stream>>>(
        Cb, s2WqT, (int)L, (int)L, (int)L, L * L, Aa * L,
        3, nullptr, 0, 0, nullptr, 0, 0,
        s1Wv, (int)Aa, L * Aa, whv, logv, L);

    // GEMM4b (batched): logits_q[m] += sum_a tanh(s2Wq[m,a] + (C^T @ s1Wv)[m,a]) * whq[a]
    gemm_nt<<<dim3((int)(Aa / BN), (int)(L / BM), (int)Bn), 256, 0, stream>>>(
        CTb, s1WvT, (int)L, (int)L, (int)L, L * L, Aa * L,
        3, nullptr, 0, 0, nullptr, 0, 0,
        s2Wq, (int)Aa, L * Aa, whq, logq, L);

    // masked softmax + weighted gather -> (v_hat, q_hat)
    softmax_gather<<<dim3((int)Bn, 2), 512, 0, stream>>>(
        logv, logq, mask1, mask2, s1, s2, out);
}

// Round 3
// 394.206 us; speedup vs baseline: 1.0555x; 1.0555x over previous
//
#include <hip/hip_runtime.h>

typedef _Float16 f16;
typedef _Float16 f16x8 __attribute__((ext_vector_type(8)));
typedef _Float16 f16x4 __attribute__((ext_vector_type(4)));
typedef float f32x4 __attribute__((ext_vector_type(4)));

#define BM 128
#define BN 128
#define BK 32

__device__ __forceinline__ float fast_tanh(float x) {
    return 1.0f - 2.0f / (__expf(2.0f * x) + 1.0f);
}

// async 16B global->LDS: LDS dest = wave-uniform base + lane*16
__device__ __forceinline__ void ld16(const void* g, void* l) {
    __builtin_amdgcn_global_load_lds(
        (const __attribute__((address_space(1))) void*)g,
        (__attribute__((address_space(3))) void*)l, 16, 0, 0);
}

__global__ __launch_bounds__(256) void f32_to_f16_k(const float* __restrict__ in,
                                                    f16* __restrict__ out, int n4) {
    int i = blockIdx.x * 256 + threadIdx.x;
    if (i >= n4) return;
    float4 v = ((const float4*)in)[i];
    f16x4 h = {(f16)v.x, (f16)v.y, (f16)v.z, (f16)v.w};
    *(f16x4*)(out + 4L * i) = h;
}

__global__ __launch_bounds__(256) void transpose_f16_k(const float* __restrict__ in,
                                                       f16* __restrict__ out, int R, int C) {
    int i = blockIdx.x * 256 + threadIdx.x;
    if (i >= R * C) return;
    int c = i / R, r = i - c * R;
    out[i] = (f16)in[r * C + c];
}

// NT GEMM: D[m][n] = sum_k A[m][k]*B[n][k], fp16 in, f32 accum, K%32==0.
// modes: 0 = store f16 C; 1 = tanh -> store f16 C + staged f16 C^T;
//        2 = store f16 C + staged f16 C^T; 3 = logits epilogue.
__global__ __launch_bounds__(256) void gemm_nt(
    const f16* __restrict__ A, const f16* __restrict__ B,
    int lda, int ldb, int K,
    long sA, long sB,
    int mode,
    f16* __restrict__ Cout, int ldc, long sC,
    f16* __restrict__ CTout, int ldct, long sCT,
    const f16* __restrict__ Sadd, int ldsa, long sS,
    const float* __restrict__ wvec,
    float* __restrict__ logits, long sL)
{
    int z = blockIdx.z;
    const f16* Ab = A + (long)z * sA;
    const f16* Bb = B + (long)z * sB;
    int m0 = blockIdx.y * BM;
    int n0 = blockIdx.x * BN;
    int tid = threadIdx.x;
    int wave = tid >> 6, lane = tid & 63;
    int quad = lane >> 4, l16 = lane & 15;
    int wm = (wave >> 1) * 64, wn = (wave & 1) * 64;

    // LDS: K-loop uses As[128][32] (8KB) + Bs[128][32] (8KB), unpadded
    // (global_load_lds needs lane-contiguous dest; XOR swizzle kills conflicts).
    // Epilogue transpose T[64][136] f16 (17408B) overlays everything.
    __shared__ __align__(16) char smem[17408];
    f16* As = (f16*)smem;
    f16* Bs = (f16*)(smem + 8192);
    f16* T  = (f16*)smem;

    f32x4 zero = {0.f, 0.f, 0.f, 0.f};
    f32x4 acc[4][4];
#pragma unroll
    for (int i = 0; i < 4; i++)
#pragma unroll
        for (int j = 0; j < 4; j++) acc[i][j] = zero;

    for (int k0 = 0; k0 < K; k0 += BK) {
        __syncthreads();
        // stage: wave w loads rows [w*32, w*32+32) of both tiles; each issue =
        // 16 rows x 64B. Global chunk = (lane&3) ^ ((row>>1)&3): the swizzle
        // spreads fragment ds_read_b128 banks -> 2-way (free, m136).
#pragma unroll
        for (int j = 0; j < 2; j++) {
            int rbase = wave * 32 + j * 16;
            int r = rbase + (lane >> 2);
            int sw = ((lane & 3) ^ ((r >> 1) & 3)) << 3;
            ld16(Ab + (long)(m0 + r) * lda + k0 + sw, As + rbase * 32);
            ld16(Bb + (long)(n0 + r) * ldb + k0 + sw, Bs + rbase * 32);
        }
        __syncthreads();

        f16x8 af[4], bfr[4];
#pragma unroll
        for (int mt = 0; mt < 4; mt++) {
            int row = wm + mt * 16 + l16;
            af[mt] = *(const f16x8*)(As + row * 32 + ((quad ^ ((row >> 1) & 3)) << 3));
        }
#pragma unroll
        for (int nt = 0; nt < 4; nt++) {
            int row = wn + nt * 16 + l16;
            bfr[nt] = *(const f16x8*)(Bs + row * 32 + ((quad ^ ((row >> 1) & 3)) << 3));
        }
#pragma unroll
        for (int mt = 0; mt < 4; mt++)
#pragma unroll
            for (int nt = 0; nt < 4; nt++)
                acc[mt][nt] = __builtin_amdgcn_mfma_f32_16x16x32_f16(af[mt], bfr[nt], acc[mt][nt], 0, 0, 0);
    }

    int gmb = m0 + wm;
    int gnb = n0 + wn;

    if (mode == 3) {
        const f16* Sb = Sadd + (long)z * sS;
        float* lg = logits + (long)z * sL;
#pragma unroll
        for (int mt = 0; mt < 4; mt++) {
            int rowb = gmb + mt * 16 + quad * 4;
            float part[4] = {0.f, 0.f, 0.f, 0.f};
#pragma unroll
            for (int nt = 0; nt < 4; nt++) {
                int col = gnb + nt * 16 + l16;
                float w = wvec[col];
#pragma unroll
                for (int r = 0; r < 4; r++) {
                    float s = (float)Sb[(long)(rowb + r) * ldsa + col];
                    part[r] += fast_tanh(s + acc[mt][nt][r]) * w;
                }
            }
#pragma unroll
            for (int off = 1; off < 16; off <<= 1) {
#pragma unroll
                for (int r = 0; r < 4; r++) part[r] += __shfl_xor(part[r], off);
            }
            if (l16 == 0) {
#pragma unroll
                for (int r = 0; r < 4; r++) atomicAdd(&lg[rowb + r], part[r]);
            }
        }
        return;
    }

    // direct C store (f16 scalar; 32B-contiguous per quad-row)
    f16* Cb = Cout + (long)z * sC;
#pragma unroll
    for (int mt = 0; mt < 4; mt++) {
        int rowb = gmb + mt * 16 + quad * 4;
#pragma unroll
        for (int nt = 0; nt < 4; nt++) {
            int col = gnb + nt * 16 + l16;
#pragma unroll
            for (int r = 0; r < 4; r++) {
                float v = acc[mt][nt][r];
                if (mode == 1) v = fast_tanh(v);
                Cb[(long)(rowb + r) * ldc + col] = (f16)v;
            }
        }
    }

    if (mode == 1 || mode == 2) {
        // staged transpose: two 64-col halves through LDS -> coalesced CT stores
        long bb = (mode == 2) ? (m0 >> 9) : z;   // GEMM3 is M-batched, GEMM2 z-batched
        int lr0  = (mode == 2) ? (m0 & 511) : m0;
        f16* CTb = CTout + bb * sCT;
#pragma unroll
        for (int h = 0; h < 2; h++) {
            __syncthreads();
            if ((wave & 1) == h) {  // waves {h, h+2}: cols h*64..h*64+63, rows wm..wm+63
#pragma unroll
                for (int mt = 0; mt < 4; mt++) {
                    int rloc = wm + mt * 16 + quad * 4;
#pragma unroll
                    for (int nt = 0; nt < 4; nt++) {
                        int cloc = nt * 16 + l16;
                        float v0 = acc[mt][nt][0], v1 = acc[mt][nt][1];
                        float v2 = acc[mt][nt][2], v3 = acc[mt][nt][3];
                        if (mode == 1) {
                            v0 = fast_tanh(v0); v1 = fast_tanh(v1);
                            v2 = fast_tanh(v2); v3 = fast_tanh(v3);
                        }
                        f16x4 hv = {(f16)v0, (f16)v1, (f16)v2, (f16)v3};
                        *(f16x4*)(T + cloc * 136 + rloc) = hv;
                    }
                }
            }
            __syncthreads();
            // cooperative coalesced store: 64 cols x 128 rows
#pragma unroll
            for (int i = 0; i < 4; i++) {
                int id = tid + i * 256;
                int c = id >> 4, r8 = (id & 15) * 8;
                f16x8 v = *(const f16x8*)(T + c * 136 + r8);
                *(f16x8*)(CTb + (long)(n0 + h * 64 + c) * ldct + lr0 + r8) = v;
            }
        }
    }
}

__device__ __forceinline__ float block_reduce(float v, float* red, int tid, bool is_max) {
#pragma unroll
    for (int off = 32; off >= 1; off >>= 1) {
        float o = __shfl_xor(v, off);
        v = is_max ? fmaxf(v, o) : (v + o);
    }
    if ((tid & 63) == 0) red[tid >> 6] = v;
    __syncthreads();
    float t = red[0];
#pragma unroll
    for (int i = 1; i < 8; i++) t = is_max ? fmaxf(t, red[i]) : (t + red[i]);
    __syncthreads();
    return t;
}

// grid (B, 2, 4): faithful masked softmax over 512 logits (recomputed per
// z-slice), then partial gather over 128 l's -> atomicAdd into out.
// NOTE: gathers from the PRISTINE f32 s1/s2 inputs — the f16 copies must not
// be used here (s1b is clobbered by C^T via the workspace alias).
__global__ __launch_bounds__(512) void softmax_gather(
    const float* __restrict__ logits_v, const float* __restrict__ logits_q,
    const int* __restrict__ mask1, const int* __restrict__ mask2,
    const float* __restrict__ s1, const float* __restrict__ s2,
    float* __restrict__ out)
{
    int b = blockIdx.x;
    int which = blockIdx.y;
    int zp = blockIdx.z;
    const float* lg = (which ? logits_q : logits_v) + (long)b * 512;
    const int*   mk = (which ? mask2 : mask1) + (long)b * 512;
    const float* S  = (which ? s2 : s1) + (long)b * 512 * 512;
    float* o = out + (long)which * 64 * 512 + (long)b * 512;

    int tid = threadIdx.x;
    __shared__ float p[512];
    __shared__ float red[8];

    float m = (float)mk[tid];
    float x = lg[tid] * m;
    float mx = block_reduce(x, red, tid, true);
    float e = __expf(x - mx);
    float S1 = block_reduce(e, red, tid, false);
    float r = (e / S1) * m;
    float S2 = block_reduce(r, red, tid, false);
    p[tid] = r / (S2 + 1e-13f);
    __syncthreads();

    float acc = 0.f;
    int l0 = zp * 128;
#pragma unroll 8
    for (int l = l0; l < l0 + 128; l++) acc += p[l] * S[(long)l * 512 + tid];
    atomicAdd(&o[tid], acc);
}

extern "C" void kernel_launch(void* const* d_in, const int* in_sizes, int n_in,
                              void* d_out, int out_size, void* d_ws, size_t ws_size,
                              hipStream_t stream) {
    const float* s1  = (const float*)d_in[0];
    const float* s2  = (const float*)d_in[1];
    const int* mask1 = (const int*)d_in[2];
    const int* mask2 = (const int*)d_in[3];
    const float* W   = (const float*)d_in[4];
    const float* Wv  = (const float*)d_in[5];
    const float* Wq  = (const float*)d_in[6];
    const float* whv = (const float*)d_in[7];
    const float* whq = (const float*)d_in[8];
    float* out = (float*)d_out;

    const long Bn = 64, L = 512, D = 512, Aa = 256;
    char* ws = (char*)d_ws;
    size_t off = 0;
    auto alloc = [&](size_t bytes) -> char* {
        char* p = ws + off;
        off += (bytes + 255) & ~(size_t)255;
        return p;
    };
    f16* s1b   = (f16*)alloc(Bn * L * D * 2);
    f16* s2b   = (f16*)alloc(Bn * L * D * 2);
    f16* s1W   = (f16*)alloc(Bn * L * D * 2);
    f16* Cb    = (f16*)alloc(Bn * L * L * 2);
    f16* s1Wv  = (f16*)alloc(Bn * L * Aa * 2);
    f16* s1WvT = (f16*)alloc(Bn * L * Aa * 2);
    f16* s2Wq  = (f16*)alloc(Bn * L * Aa * 2);
    f16* s2WqT = (f16*)alloc(Bn * L * Aa * 2);
    f16* WTb   = (f16*)alloc(D * D * 2);
    f16* WvTb  = (f16*)alloc(D * Aa * 2);
    f16* WqTb  = (f16*)alloc(D * Aa * 2);
    float* logv = (float*)alloc(2 * Bn * L * 4);
    float* logq = logv + Bn * L;
    f16* CTb = s1b;  // alias: s1b dead (as f16 input) before GEMM2 writes C^T
    if (ws_size < off) return;

    int n4 = (int)(Bn * L * D / 4);
    f32_to_f16_k<<<dim3((n4 + 255) / 256), 256, 0, stream>>>(s1, s1b, n4);
    f32_to_f16_k<<<dim3((n4 + 255) / 256), 256, 0, stream>>>(s2, s2b, n4);
    transpose_f16_k<<<dim3((int)(D * D + 255) / 256), 256, 0, stream>>>(W, WTb, (int)D, (int)D);
    transpose_f16_k<<<dim3((int)(D * Aa + 255) / 256), 256, 0, stream>>>(Wv, WvTb, (int)D, (int)Aa);
    transpose_f16_k<<<dim3((int)(D * Aa + 255) / 256), 256, 0, stream>>>(Wq, WqTb, (int)D, (int)Aa);
    hipMemsetAsync(logv, 0, 2 * Bn * L * 4, stream);
    hipMemsetAsync(out, 0, (size_t)out_size * 4, stream);

    // GEMM1: s1W = s1 @ W
    gemm_nt<<<dim3((int)(D / BN), (int)(Bn * L / BM), 1), 256, 0, stream>>>(
        s1b, WTb, (int)D, (int)D, (int)D, 0, 0,
        0, s1W, (int)D, 0,
        nullptr, 0, 0, nullptr, 0, 0, nullptr, nullptr, 0);

    // GEMM3a: s1Wv(+T) = s1 @ Wv
    gemm_nt<<<dim3((int)(Aa / BN), (int)(Bn * L / BM), 1), 256, 0, stream>>>(
        s1b, WvTb, (int)D, (int)D, (int)D, 0, 0,
        2, s1Wv, (int)Aa, 0,
        s1WvT, (int)L, L * Aa, nullptr, 0, 0, nullptr, nullptr, 0);

    // GEMM3b: s2Wq(+T) = s2 @ Wq
    gemm_nt<<<dim3((int)(Aa / BN), (int)(Bn * L / BM), 1), 256, 0, stream>>>(
        s2b, WqTb, (int)D, (int)D, (int)D, 0, 0,
        2, s2Wq, (int)Aa, 0,
        s2WqT, (int)L, L * Aa, nullptr, 0, 0, nullptr, nullptr, 0);

    // GEMM2 (batched): C = tanh(s1W @ s2^T) + staged C^T
    gemm_nt<<<dim3((int)(L / BN), (int)(L / BM), (int)Bn), 256, 0, stream>>>(
        s1W, s2b, (int)D, (int)D, (int)D, L * D, L * D,
        1, Cb, (int)L, L * L,
        CTb, (int)L, L * L, nullptr, 0, 0, nullptr, nullptr, 0);

    // GEMM4a: logits_v += rowsum tanh(s1Wv + C @ s2Wq) * whv
    gemm_nt<<<dim3((int)(Aa / BN), (int)(L / BM), (int)Bn), 256, 0, stream>>>(
        Cb, s2WqT, (int)L, (int)L, (int)L, L * L, Aa * L,
        3, nullptr, 0, 0, nullptr, 0, 0,
        s1Wv, (int)Aa, L * Aa, whv, logv, L);

    // GEMM4b: logits_q += rowsum tanh(s2Wq + C^T @ s1Wv) * whq
    gemm_nt<<<dim3((int)(Aa / BN), (int)(L / BM), (int)Bn), 256, 0, stream>>>(
        CTb, s1WvT, (int)L, (int)L, (int)L, L * L, Aa * L,
        3, nullptr, 0, 0, nullptr, 0, 0,
        s2Wq, (int)Aa, L * Aa, whq, logq, L);

    softmax_gather<<<dim3((int)Bn, 2, 4), 512, 0, stream>>>(
        logv, logq, mask1, mask2, s1, s2, out);
}

// Round 4
// 360.002 us; speedup vs baseline: 1.1558x; 1.0950x over previous
//
#include <hip/hip_runtime.h>

typedef _Float16 f16;
typedef _Float16 f16x8 __attribute__((ext_vector_type(8)));
typedef _Float16 f16x4 __attribute__((ext_vector_type(4)));
typedef float f32x4 __attribute__((ext_vector_type(4)));

#define BM 128
#define BN 128
#define BK 32

__device__ __forceinline__ float fast_tanh(float x) {
    return 1.0f - 2.0f / (__expf(2.0f * x) + 1.0f);
}

// async 16B global->LDS: LDS dest = wave-uniform base + lane*16
__device__ __forceinline__ void ld16(const void* g, void* l) {
    __builtin_amdgcn_global_load_lds(
        (const __attribute__((address_space(1))) void*)g,
        (__attribute__((address_space(3))) void*)l, 16, 0, 0);
}

__global__ __launch_bounds__(256) void f32_to_f16_k(const float* __restrict__ in,
                                                    f16* __restrict__ out, int n4) {
    int i = blockIdx.x * 256 + threadIdx.x;
    if (i >= n4) return;
    float4 v = ((const float4*)in)[i];
    f16x4 h = {(f16)v.x, (f16)v.y, (f16)v.z, (f16)v.w};
    *(f16x4*)(out + 4L * i) = h;
}

__global__ __launch_bounds__(256) void transpose_f16_k(const float* __restrict__ in,
                                                       f16* __restrict__ out, int R, int C) {
    int i = blockIdx.x * 256 + threadIdx.x;
    if (i >= R * C) return;
    int c = i / R, r = i - c * R;
    out[i] = (f16)in[r * C + c];
}

// NT GEMM: D[m][n] = sum_k A[m][k]*B[n][k], fp16 in, f32 accum, K%32==0.
// Double-buffered LDS K-loop with raw s_barrier + vmcnt(4) prefetch wait:
// per iter [barrier_A; DMA tile k+1; waitcnt vmcnt(4); barrier_B; compute k].
// Tile-k DMAs were issued one full compute phase earlier -> latency hidden.
// modes: 0 = store f16 C; 1 = tanh -> store f16 C + staged f16 C^T;
//        2 = store f16 C + staged f16 C^T; 3 = logits epilogue.
__global__ __launch_bounds__(256) void gemm_nt(
    const f16* __restrict__ A, const f16* __restrict__ B,
    int lda, int ldb, int K,
    long sA, long sB,
    int mode,
    f16* __restrict__ Cout, int ldc, long sC,
    f16* __restrict__ CTout, int ldct, long sCT,
    const f16* __restrict__ Sadd, int ldsa, long sS,
    const float* __restrict__ wvec,
    float* __restrict__ logits, long sL)
{
    int z = blockIdx.z;
    const f16* Ab = A + (long)z * sA;
    const f16* Bb = B + (long)z * sB;
    int m0 = blockIdx.y * BM;
    int n0 = blockIdx.x * BN;
    int tid = threadIdx.x;
    int wave = tid >> 6, lane = tid & 63;
    int quad = lane >> 4, l16 = lane & 15;
    int wm = (wave >> 1) * 64, wn = (wave & 1) * 64;

    // LDS: 2 x (As 8KB + Bs 8KB) = 32KB double buffer; epilogue T overlays.
    __shared__ __align__(16) char smem[32768];
    f16* T = (f16*)smem;

    f32x4 zero = {0.f, 0.f, 0.f, 0.f};
    f32x4 acc[4][4];
#pragma unroll
    for (int i = 0; i < 4; i++)
#pragma unroll
        for (int j = 0; j < 4; j++) acc[i][j] = zero;

    // stage tile at k-offset k0 into buffer buf (4 ld16 issues per thread-quad
    // pattern; LDS dest is wave-uniform base + lane*16 as required).
    auto stage = [&](int buf, int k0) {
        f16* As = (f16*)(smem + buf * 16384);
        f16* Bs = (f16*)(smem + buf * 16384 + 8192);
#pragma unroll
        for (int j = 0; j < 2; j++) {
            int rbase = wave * 32 + j * 16;
            int r = rbase + (lane >> 2);
            int sw = ((lane & 3) ^ ((r >> 1) & 3)) << 3;
            ld16(Ab + (long)(m0 + r) * lda + k0 + sw, As + rbase * 32);
            ld16(Bb + (long)(n0 + r) * ldb + k0 + sw, Bs + rbase * 32);
        }
    };

    const int NK = K >> 5;
    stage(0, 0);
    for (int ki = 0; ki < NK; ki++) {
        int cur = ki & 1;
        // barrier_A: all waves done reading buf[1-cur] (iter ki-1) before we
        // DMA into it for tile ki+1.
        __builtin_amdgcn_s_barrier();
        asm volatile("" ::: "memory");
        if (ki + 1 < NK) {
            stage(1 - cur, (ki + 1) << 5);
            __builtin_amdgcn_s_waitcnt(0xF74);  // vmcnt(4): tile-ki DMAs done
        } else {
            __builtin_amdgcn_s_waitcnt(0xF70);  // vmcnt(0): last tile
        }
        // barrier_B: all waves' tile-ki DMAs complete.
        __builtin_amdgcn_s_barrier();
        asm volatile("" ::: "memory");

        const f16* As = (const f16*)(smem + cur * 16384);
        const f16* Bs = (const f16*)(smem + cur * 16384 + 8192);
        f16x8 af[4], bfr[4];
#pragma unroll
        for (int mt = 0; mt < 4; mt++) {
            int row = wm + mt * 16 + l16;
            af[mt] = *(const f16x8*)(As + row * 32 + ((quad ^ ((row >> 1) & 3)) << 3));
        }
#pragma unroll
        for (int nt = 0; nt < 4; nt++) {
            int row = wn + nt * 16 + l16;
            bfr[nt] = *(const f16x8*)(Bs + row * 32 + ((quad ^ ((row >> 1) & 3)) << 3));
        }
#pragma unroll
        for (int mt = 0; mt < 4; mt++)
#pragma unroll
            for (int nt = 0; nt < 4; nt++)
                acc[mt][nt] = __builtin_amdgcn_mfma_f32_16x16x32_f16(af[mt], bfr[nt], acc[mt][nt], 0, 0, 0);
        asm volatile("" ::: "memory");
    }

    int gmb = m0 + wm;
    int gnb = n0 + wn;

    if (mode == 3) {
        const f16* Sb = Sadd + (long)z * sS;
        float* lg = logits + (long)z * sL;
#pragma unroll
        for (int mt = 0; mt < 4; mt++) {
            int rowb = gmb + mt * 16 + quad * 4;
            float part[4] = {0.f, 0.f, 0.f, 0.f};
#pragma unroll
            for (int nt = 0; nt < 4; nt++) {
                int col = gnb + nt * 16 + l16;
                float w = wvec[col];
#pragma unroll
                for (int r = 0; r < 4; r++) {
                    float s = (float)Sb[(long)(rowb + r) * ldsa + col];
                    part[r] += fast_tanh(s + acc[mt][nt][r]) * w;
                }
            }
#pragma unroll
            for (int off = 1; off < 16; off <<= 1) {
#pragma unroll
                for (int r = 0; r < 4; r++) part[r] += __shfl_xor(part[r], off);
            }
            if (l16 == 0) {
#pragma unroll
                for (int r = 0; r < 4; r++) atomicAdd(&lg[rowb + r], part[r]);
            }
        }
        return;
    }

    // convert (and tanh for mode 1) ONCE into f16 regs; reuse for both stores
    f16x4 hreg[4][4];
#pragma unroll
    for (int mt = 0; mt < 4; mt++)
#pragma unroll
        for (int nt = 0; nt < 4; nt++) {
            float v0 = acc[mt][nt][0], v1 = acc[mt][nt][1];
            float v2 = acc[mt][nt][2], v3 = acc[mt][nt][3];
            if (mode == 1) {
                v0 = fast_tanh(v0); v1 = fast_tanh(v1);
                v2 = fast_tanh(v2); v3 = fast_tanh(v3);
            }
            f16x4 hv = {(f16)v0, (f16)v1, (f16)v2, (f16)v3};
            hreg[mt][nt] = hv;
        }

    // direct C store
    f16* Cb = Cout + (long)z * sC;
#pragma unroll
    for (int mt = 0; mt < 4; mt++) {
        int rowb = gmb + mt * 16 + quad * 4;
#pragma unroll
        for (int nt = 0; nt < 4; nt++) {
            int col = gnb + nt * 16 + l16;
#pragma unroll
            for (int r = 0; r < 4; r++)
                Cb[(long)(rowb + r) * ldc + col] = hreg[mt][nt][r];
        }
    }

    if (mode == 1 || mode == 2) {
        // staged transpose: two 64-col halves through LDS -> coalesced CT stores
        long bb = (mode == 2) ? (m0 >> 9) : z;   // GEMM3 is M-batched, GEMM2 z-batched
        int lr0  = (mode == 2) ? (m0 & 511) : m0;
        f16* CTb = CTout + bb * sCT;
#pragma unroll
        for (int h = 0; h < 2; h++) {
            __syncthreads();
            if ((wave & 1) == h) {  // waves {h, h+2}: cols h*64..h*64+63, rows wm..wm+63
#pragma unroll
                for (int mt = 0; mt < 4; mt++) {
                    int rloc = wm + mt * 16 + quad * 4;
#pragma unroll
                    for (int nt = 0; nt < 4; nt++) {
                        int cloc = nt * 16 + l16;
                        *(f16x4*)(T + cloc * 136 + rloc) = hreg[mt][nt];
                    }
                }
            }
            __syncthreads();
            // cooperative coalesced store: 64 cols x 128 rows
#pragma unroll
            for (int i = 0; i < 4; i++) {
                int id = tid + i * 256;
                int c = id >> 4, r8 = (id & 15) * 8;
                f16x8 v = *(const f16x8*)(T + c * 136 + r8);
                *(f16x8*)(CTb + (long)(n0 + h * 64 + c) * ldct + lr0 + r8) = v;
            }
        }
    }
}

__device__ __forceinline__ float block_reduce(float v, float* red, int tid, bool is_max) {
#pragma unroll
    for (int off = 32; off >= 1; off >>= 1) {
        float o = __shfl_xor(v, off);
        v = is_max ? fmaxf(v, o) : (v + o);
    }
    if ((tid & 63) == 0) red[tid >> 6] = v;
    __syncthreads();
    float t = red[0];
#pragma unroll
    for (int i = 1; i < 8; i++) t = is_max ? fmaxf(t, red[i]) : (t + red[i]);
    __syncthreads();
    return t;
}

// grid (B, 2, 4): faithful masked softmax over 512 logits (recomputed per
// z-slice), then partial gather over 128 l's -> atomicAdd into out.
// use_h: gather from f16 copies (only safe when CT has a dedicated buffer).
__global__ __launch_bounds__(512) void softmax_gather(
    const float* __restrict__ logits_v, const float* __restrict__ logits_q,
    const int* __restrict__ mask1, const int* __restrict__ mask2,
    const float* __restrict__ s1f, const float* __restrict__ s2f,
    const f16* __restrict__ s1h, const f16* __restrict__ s2h, int use_h,
    float* __restrict__ out)
{
    int b = blockIdx.x;
    int which = blockIdx.y;
    int zp = blockIdx.z;
    const float* lg = (which ? logits_q : logits_v) + (long)b * 512;
    const int*   mk = (which ? mask2 : mask1) + (long)b * 512;
    float* o = out + (long)which * 64 * 512 + (long)b * 512;

    int tid = threadIdx.x;
    __shared__ float p[512];
    __shared__ float red[8];

    float m = (float)mk[tid];
    float x = lg[tid] * m;
    float mx = block_reduce(x, red, tid, true);
    float e = __expf(x - mx);
    float S1 = block_reduce(e, red, tid, false);
    float r = (e / S1) * m;
    float S2 = block_reduce(r, red, tid, false);
    p[tid] = r / (S2 + 1e-13f);
    __syncthreads();

    float acc = 0.f;
    int l0 = zp * 128;
    if (use_h) {
        const f16* S = (which ? s2h : s1h) + (long)b * 512 * 512;
#pragma unroll 8
        for (int l = l0; l < l0 + 128; l++) acc += p[l] * (float)S[(long)l * 512 + tid];
    } else {
        const float* S = (which ? s2f : s1f) + (long)b * 512 * 512;
#pragma unroll 8
        for (int l = l0; l < l0 + 128; l++) acc += p[l] * S[(long)l * 512 + tid];
    }
    atomicAdd(&o[tid], acc);
}

extern "C" void kernel_launch(void* const* d_in, const int* in_sizes, int n_in,
                              void* d_out, int out_size, void* d_ws, size_t ws_size,
                              hipStream_t stream) {
    const float* s1  = (const float*)d_in[0];
    const float* s2  = (const float*)d_in[1];
    const int* mask1 = (const int*)d_in[2];
    const int* mask2 = (const int*)d_in[3];
    const float* W   = (const float*)d_in[4];
    const float* Wv  = (const float*)d_in[5];
    const float* Wq  = (const float*)d_in[6];
    const float* whv = (const float*)d_in[7];
    const float* whq = (const float*)d_in[8];
    float* out = (float*)d_out;

    const long Bn = 64, L = 512, D = 512, Aa = 256;
    char* ws = (char*)d_ws;
    size_t off = 0;
    auto alloc = [&](size_t bytes) -> char* {
        char* p = ws + off;
        off += (bytes + 255) & ~(size_t)255;
        return p;
    };
    f16* s1b   = (f16*)alloc(Bn * L * D * 2);
    f16* s2b   = (f16*)alloc(Bn * L * D * 2);
    f16* s1W   = (f16*)alloc(Bn * L * D * 2);
    f16* Cb    = (f16*)alloc(Bn * L * L * 2);
    f16* s1Wv  = (f16*)alloc(Bn * L * Aa * 2);
    f16* s1WvT = (f16*)alloc(Bn * L * Aa * 2);
    f16* s2Wq  = (f16*)alloc(Bn * L * Aa * 2);
    f16* s2WqT = (f16*)alloc(Bn * L * Aa * 2);
    f16* WTb   = (f16*)alloc(D * D * 2);
    f16* WvTb  = (f16*)alloc(D * Aa * 2);
    f16* WqTb  = (f16*)alloc(D * Aa * 2);
    float* logv = (float*)alloc(2 * Bn * L * 4);
    float* logq = logv + Bn * L;
    size_t base_off = off;
    f16* CTded = (f16*)alloc(Bn * L * L * 2);  // optional dedicated CT
    if (ws_size < base_off) return;
    int use_ded = (ws_size >= off) ? 1 : 0;
    f16* CTb = use_ded ? CTded : s1b;  // fallback: alias s1b (dead as f16 input)

    int n4 = (int)(Bn * L * D / 4);
    f32_to_f16_k<<<dim3((n4 + 255) / 256), 256, 0, stream>>>(s1, s1b, n4);
    f32_to_f16_k<<<dim3((n4 + 255) / 256), 256, 0, stream>>>(s2, s2b, n4);
    transpose_f16_k<<<dim3((int)(D * D + 255) / 256), 256, 0, stream>>>(W, WTb, (int)D, (int)D);
    transpose_f16_k<<<dim3((int)(D * Aa + 255) / 256), 256, 0, stream>>>(Wv, WvTb, (int)D, (int)Aa);
    transpose_f16_k<<<dim3((int)(D * Aa + 255) / 256), 256, 0, stream>>>(Wq, WqTb, (int)D, (int)Aa);
    hipMemsetAsync(logv, 0, 2 * Bn * L * 4, stream);
    hipMemsetAsync(out, 0, (size_t)out_size * 4, stream);

    // GEMM1: s1W = s1 @ W
    gemm_nt<<<dim3((int)(D / BN), (int)(Bn * L / BM), 1), 256, 0, stream>>>(
        s1b, WTb, (int)D, (int)D, (int)D, 0, 0,
        0, s1W, (int)D, 0,
        nullptr, 0, 0, nullptr, 0, 0, nullptr, nullptr, 0);

    // GEMM3a: s1Wv(+T) = s1 @ Wv
    gemm_nt<<<dim3((int)(Aa / BN), (int)(Bn * L / BM), 1), 256, 0, stream>>>(
        s1b, WvTb, (int)D, (int)D, (int)D, 0, 0,
        2, s1Wv, (int)Aa, 0,
        s1WvT, (int)L, L * Aa, nullptr, 0, 0, nullptr, nullptr, 0);

    // GEMM3b: s2Wq(+T) = s2 @ Wq
    gemm_nt<<<dim3((int)(Aa / BN), (int)(Bn * L / BM), 1), 256, 0, stream>>>(
        s2b, WqTb, (int)D, (int)D, (int)D, 0, 0,
        2, s2Wq, (int)Aa, 0,
        s2WqT, (int)L, L * Aa, nullptr, 0, 0, nullptr, nullptr, 0);

    // GEMM2 (batched): C = tanh(s1W @ s2^T) + staged C^T
    gemm_nt<<<dim3((int)(L / BN), (int)(L / BM), (int)Bn), 256, 0, stream>>>(
        s1W, s2b, (int)D, (int)D, (int)D, L * D, L * D,
        1, Cb, (int)L, L * L,
        CTb, (int)L, L * L, nullptr, 0, 0, nullptr, nullptr, 0);

    // GEMM4a: logits_v += rowsum tanh(s1Wv + C @ s2Wq) * whv
    gemm_nt<<<dim3((int)(Aa / BN), (int)(L / BM), (int)Bn), 256, 0, stream>>>(
        Cb, s2WqT, (int)L, (int)L, (int)L, L * L, Aa * L,
        3, nullptr, 0, 0, nullptr, 0, 0,
        s1Wv, (int)Aa, L * Aa, whv, logv, L);

    // GEMM4b: logits_q += rowsum tanh(s2Wq + C^T @ s1Wv) * whq
    gemm_nt<<<dim3((int)(Aa / BN), (int)(L / BM), (int)Bn), 256, 0, stream>>>(
        CTb, s1WvT, (int)L, (int)L, (int)L, L * L, Aa * L,
        3, nullptr, 0, 0, nullptr, 0, 0,
        s2Wq, (int)Aa, L * Aa, whq, logq, L);

    softmax_gather<<<dim3((int)Bn, 2, 4), 512, 0, stream>>>(
        logv, logq, mask1, mask2, s1, s2, s1b, s2b, use_ded, out);
}

// Round 5
// 335.898 us; speedup vs baseline: 1.2388x; 1.0718x over previous
//
#include <hip/hip_runtime.h>

typedef _Float16 f16;
typedef _Float16 f16x8 __attribute__((ext_vector_type(8)));
typedef _Float16 f16x4 __attribute__((ext_vector_type(4)));
typedef float f32x4 __attribute__((ext_vector_type(4)));

#define BM 128
#define BN 128
#define BK 32

__device__ __forceinline__ float fast_tanh(float x) {
    return 1.0f - 2.0f / (__expf(2.0f * x) + 1.0f);
}

// async 16B global->LDS: LDS dest = wave-uniform base + lane*16
__device__ __forceinline__ void ld16(const void* g, void* l) {
    __builtin_amdgcn_global_load_lds(
        (const __attribute__((address_space(1))) void*)g,
        (__attribute__((address_space(3))) void*)l, 16, 0, 0);
}

__global__ __launch_bounds__(256) void f32_to_f16_k(const float* __restrict__ in,
                                                    f16* __restrict__ out, int n4) {
    int i = blockIdx.x * 256 + threadIdx.x;
    if (i >= n4) return;
    float4 v = ((const float4*)in)[i];
    f16x4 h = {(f16)v.x, (f16)v.y, (f16)v.z, (f16)v.w};
    *(f16x4*)(out + 4L * i) = h;
}

__global__ __launch_bounds__(256) void transpose_f16_k(const float* __restrict__ in,
                                                       f16* __restrict__ out, int R, int C) {
    int i = blockIdx.x * 256 + threadIdx.x;
    if (i >= R * C) return;
    int c = i / R, r = i - c * R;
    out[i] = (f16)in[r * C + c];
}

// NT GEMM: D[m][n] = sum_k A[m][k]*B[n][k], fp16 in, f32 accum, K%32==0.
// Double-buffered LDS K-loop, raw s_barrier + vmcnt(4) prefetch wait.
// swz_log2 >= 0: XCD-cluster swizzle — all tiles of one batch z share bid%8
// (per-z A/B panels stay resident in ONE XCD's L2). tiles/z = 1<<swz_log2,
// requires gridDim.z % 8 == 0.
// modes: 0 = store f16 C; 1 = tanh -> store f16 C + staged f16 C^T;
//        2 = store f16 C + staged f16 C^T; 3 = logits epilogue.
__global__ __launch_bounds__(256, 3) void gemm_nt(
    const f16* __restrict__ A, const f16* __restrict__ B,
    int lda, int ldb, int K,
    long sA, long sB,
    int mode, int swz_log2,
    f16* __restrict__ Cout, int ldc, long sC,
    f16* __restrict__ CTout, int ldct, long sCT,
    const f16* __restrict__ Sadd, int ldsa, long sS,
    const float* __restrict__ wvec,
    float* __restrict__ logits, long sL)
{
    int bx = blockIdx.x, by = blockIdx.y, bz = blockIdx.z;
    if (swz_log2 >= 0) {
        int bid = blockIdx.x + gridDim.x * (blockIdx.y + gridDim.y * blockIdx.z);
        int tg = bid >> 3;
        bz = (bid & 7) + 8 * (tg >> swz_log2);
        int t = tg & ((1 << swz_log2) - 1);
        bx = t % gridDim.x;
        by = t / gridDim.x;
    }
    const f16* Ab = A + (long)bz * sA;
    const f16* Bb = B + (long)bz * sB;
    int m0 = by * BM;
    int n0 = bx * BN;
    int tid = threadIdx.x;
    int wave = tid >> 6, lane = tid & 63;
    int quad = lane >> 4, l16 = lane & 15;
    int wm = (wave >> 1) * 64, wn = (wave & 1) * 64;

    // LDS: 2 x (As 8KB + Bs 8KB) = 32KB double buffer; epilogue T overlays.
    __shared__ __align__(16) char smem[32768];
    f16* T = (f16*)smem;

    f32x4 zero = {0.f, 0.f, 0.f, 0.f};
    f32x4 acc[4][4];
#pragma unroll
    for (int i = 0; i < 4; i++)
#pragma unroll
        for (int j = 0; j < 4; j++) acc[i][j] = zero;

    auto stage = [&](int buf, int k0) {
        f16* As = (f16*)(smem + buf * 16384);
        f16* Bs = (f16*)(smem + buf * 16384 + 8192);
#pragma unroll
        for (int j = 0; j < 2; j++) {
            int rbase = wave * 32 + j * 16;
            int r = rbase + (lane >> 2);
            int sw = ((lane & 3) ^ ((r >> 1) & 3)) << 3;
            ld16(Ab + (long)(m0 + r) * lda + k0 + sw, As + rbase * 32);
            ld16(Bb + (long)(n0 + r) * ldb + k0 + sw, Bs + rbase * 32);
        }
    };

    const int NK = K >> 5;
    stage(0, 0);
    for (int ki = 0; ki < NK; ki++) {
        int cur = ki & 1;
        __builtin_amdgcn_s_barrier();          // all waves done reading buf[1-cur]
        asm volatile("" ::: "memory");
        if (ki + 1 < NK) {
            stage(1 - cur, (ki + 1) << 5);
            __builtin_amdgcn_s_waitcnt(0xF74); // vmcnt(4): tile-ki DMAs done
        } else {
            __builtin_amdgcn_s_waitcnt(0xF70); // vmcnt(0): last tile
        }
        __builtin_amdgcn_s_barrier();          // tile-ki visible to all waves
        asm volatile("" ::: "memory");

        const f16* As = (const f16*)(smem + cur * 16384);
        const f16* Bs = (const f16*)(smem + cur * 16384 + 8192);
        f16x8 af[4], bfr[4];
#pragma unroll
        for (int mt = 0; mt < 4; mt++) {
            int row = wm + mt * 16 + l16;
            af[mt] = *(const f16x8*)(As + row * 32 + ((quad ^ ((row >> 1) & 3)) << 3));
        }
#pragma unroll
        for (int nt = 0; nt < 4; nt++) {
            int row = wn + nt * 16 + l16;
            bfr[nt] = *(const f16x8*)(Bs + row * 32 + ((quad ^ ((row >> 1) & 3)) << 3));
        }
#pragma unroll
        for (int mt = 0; mt < 4; mt++)
#pragma unroll
            for (int nt = 0; nt < 4; nt++)
                acc[mt][nt] = __builtin_amdgcn_mfma_f32_16x16x32_f16(af[mt], bfr[nt], acc[mt][nt], 0, 0, 0);
        asm volatile("" ::: "memory");
    }

    int gmb = m0 + wm;
    int gnb = n0 + wn;

    if (mode == 3) {
        const f16* Sb = Sadd + (long)bz * sS;
        float* lg = logits + (long)bz * sL;
#pragma unroll
        for (int mt = 0; mt < 4; mt++) {
            int rowb = gmb + mt * 16 + quad * 4;
            float part[4] = {0.f, 0.f, 0.f, 0.f};
#pragma unroll
            for (int nt = 0; nt < 4; nt++) {
                int col = gnb + nt * 16 + l16;
                float w = wvec[col];
#pragma unroll
                for (int r = 0; r < 4; r++) {
                    float s = (float)Sb[(long)(rowb + r) * ldsa + col];
                    part[r] += fast_tanh(s + acc[mt][nt][r]) * w;
                }
            }
#pragma unroll
            for (int off = 1; off < 16; off <<= 1) {
#pragma unroll
                for (int r = 0; r < 4; r++) part[r] += __shfl_xor(part[r], off);
            }
            if (l16 == 0) {
#pragma unroll
                for (int r = 0; r < 4; r++) atomicAdd(&lg[rowb + r], part[r]);
            }
        }
        return;
    }

    // convert (and tanh for mode 1) ONCE into f16 regs; reuse for both stores
    f16x4 hreg[4][4];
#pragma unroll
    for (int mt = 0; mt < 4; mt++)
#pragma unroll
        for (int nt = 0; nt < 4; nt++) {
            float v0 = acc[mt][nt][0], v1 = acc[mt][nt][1];
            float v2 = acc[mt][nt][2], v3 = acc[mt][nt][3];
            if (mode == 1) {
                v0 = fast_tanh(v0); v1 = fast_tanh(v1);
                v2 = fast_tanh(v2); v3 = fast_tanh(v3);
            }
            f16x4 hv = {(f16)v0, (f16)v1, (f16)v2, (f16)v3};
            hreg[mt][nt] = hv;
        }

    // direct C store
    f16* Cb = Cout + (long)bz * sC;
#pragma unroll
    for (int mt = 0; mt < 4; mt++) {
        int rowb = gmb + mt * 16 + quad * 4;
#pragma unroll
        for (int nt = 0; nt < 4; nt++) {
            int col = gnb + nt * 16 + l16;
#pragma unroll
            for (int r = 0; r < 4; r++)
                Cb[(long)(rowb + r) * ldc + col] = hreg[mt][nt][r];
        }
    }

    if (mode == 1 || mode == 2) {
        // staged transpose: two 64-col halves through LDS -> coalesced CT stores
        long bb = (mode == 2) ? (m0 >> 9) : bz;  // GEMM3 is M-batched, GEMM2 z-batched
        int lr0  = (mode == 2) ? (m0 & 511) : m0;
        f16* CTb = CTout + bb * sCT;
#pragma unroll
        for (int h = 0; h < 2; h++) {
            __syncthreads();
            if ((wave & 1) == h) {
#pragma unroll
                for (int mt = 0; mt < 4; mt++) {
                    int rloc = wm + mt * 16 + quad * 4;
#pragma unroll
                    for (int nt = 0; nt < 4; nt++) {
                        int cloc = nt * 16 + l16;
                        *(f16x4*)(T + cloc * 136 + rloc) = hreg[mt][nt];
                    }
                }
            }
            __syncthreads();
#pragma unroll
            for (int i = 0; i < 4; i++) {
                int id = tid + i * 256;
                int c = id >> 4, r8 = (id & 15) * 8;
                f16x8 v = *(const f16x8*)(T + c * 136 + r8);
                *(f16x8*)(CTb + (long)(n0 + h * 64 + c) * ldct + lr0 + r8) = v;
            }
        }
    }
}

__device__ __forceinline__ float block_reduce(float v, float* red, int tid, bool is_max) {
#pragma unroll
    for (int off = 32; off >= 1; off >>= 1) {
        float o = __shfl_xor(v, off);
        v = is_max ? fmaxf(v, o) : (v + o);
    }
    if ((tid & 63) == 0) red[tid >> 6] = v;
    __syncthreads();
    float t = red[0];
#pragma unroll
    for (int i = 1; i < 8; i++) t = is_max ? fmaxf(t, red[i]) : (t + red[i]);
    __syncthreads();
    return t;
}

// grid (B, 2, 4): faithful masked softmax over 512 logits (recomputed per
// z-slice), then partial gather over 128 l's -> atomicAdd into out.
// use_h: gather from f16 copies (only safe when CT has a dedicated buffer).
__global__ __launch_bounds__(512) void softmax_gather(
    const float* __restrict__ logits_v, const float* __restrict__ logits_q,
    const int* __restrict__ mask1, const int* __restrict__ mask2,
    const float* __restrict__ s1f, const float* __restrict__ s2f,
    const f16* __restrict__ s1h, const f16* __restrict__ s2h, int use_h,
    float* __restrict__ out)
{
    int b = blockIdx.x;
    int which = blockIdx.y;
    int zp = blockIdx.z;
    const float* lg = (which ? logits_q : logits_v) + (long)b * 512;
    const int*   mk = (which ? mask2 : mask1) + (long)b * 512;
    float* o = out + (long)which * 64 * 512 + (long)b * 512;

    int tid = threadIdx.x;
    __shared__ float p[512];
    __shared__ float red[8];

    float m = (float)mk[tid];
    float x = lg[tid] * m;
    float mx = block_reduce(x, red, tid, true);
    float e = __expf(x - mx);
    float S1 = block_reduce(e, red, tid, false);
    float r = (e / S1) * m;
    float S2 = block_reduce(r, red, tid, false);
    p[tid] = r / (S2 + 1e-13f);
    __syncthreads();

    float acc = 0.f;
    int l0 = zp * 128;
    if (use_h) {
        const f16* S = (which ? s2h : s1h) + (long)b * 512 * 512;
#pragma unroll 8
        for (int l = l0; l < l0 + 128; l++) acc += p[l] * (float)S[(long)l * 512 + tid];
    } else {
        const float* S = (which ? s2f : s1f) + (long)b * 512 * 512;
#pragma unroll 8
        for (int l = l0; l < l0 + 128; l++) acc += p[l] * S[(long)l * 512 + tid];
    }
    atomicAdd(&o[tid], acc);
}

extern "C" void kernel_launch(void* const* d_in, const int* in_sizes, int n_in,
                              void* d_out, int out_size, void* d_ws, size_t ws_size,
                              hipStream_t stream) {
    const float* s1  = (const float*)d_in[0];
    const float* s2  = (const float*)d_in[1];
    const int* mask1 = (const int*)d_in[2];
    const int* mask2 = (const int*)d_in[3];
    const float* W   = (const float*)d_in[4];
    const float* Wv  = (const float*)d_in[5];
    const float* Wq  = (const float*)d_in[6];
    const float* whv = (const float*)d_in[7];
    const float* whq = (const float*)d_in[8];
    float* out = (float*)d_out;

    const long Bn = 64, L = 512, D = 512, Aa = 256;
    char* ws = (char*)d_ws;
    size_t off = 0;
    auto alloc = [&](size_t bytes) -> char* {
        char* p = ws + off;
        off += (bytes + 255) & ~(size_t)255;
        return p;
    };
    f16* s1b   = (f16*)alloc(Bn * L * D * 2);
    f16* s2b   = (f16*)alloc(Bn * L * D * 2);
    f16* s1W   = (f16*)alloc(Bn * L * D * 2);
    f16* Cb    = (f16*)alloc(Bn * L * L * 2);
    f16* s1Wv  = (f16*)alloc(Bn * L * Aa * 2);
    f16* s1WvT = (f16*)alloc(Bn * L * Aa * 2);
    f16* s2Wq  = (f16*)alloc(Bn * L * Aa * 2);
    f16* s2WqT = (f16*)alloc(Bn * L * Aa * 2);
    f16* WTb   = (f16*)alloc(D * D * 2);
    f16* WvTb  = (f16*)alloc(D * Aa * 2);
    f16* WqTb  = (f16*)alloc(D * Aa * 2);
    float* logv = (float*)alloc(2 * Bn * L * 4);
    float* logq = logv + Bn * L;
    size_t base_off = off;
    f16* CTded = (f16*)alloc(Bn * L * L * 2);  // optional dedicated CT
    if (ws_size < base_off) return;
    int use_ded = (ws_size >= off) ? 1 : 0;
    f16* CTb = use_ded ? CTded : s1b;  // fallback: alias s1b (dead as f16 input)

    int n4 = (int)(Bn * L * D / 4);
    f32_to_f16_k<<<dim3((n4 + 255) / 256), 256, 0, stream>>>(s1, s1b, n4);
    f32_to_f16_k<<<dim3((n4 + 255) / 256), 256, 0, stream>>>(s2, s2b, n4);
    transpose_f16_k<<<dim3((int)(D * D + 255) / 256), 256, 0, stream>>>(W, WTb, (int)D, (int)D);
    transpose_f16_k<<<dim3((int)(D * Aa + 255) / 256), 256, 0, stream>>>(Wv, WvTb, (int)D, (int)Aa);
    transpose_f16_k<<<dim3((int)(D * Aa + 255) / 256), 256, 0, stream>>>(Wq, WqTb, (int)D, (int)Aa);
    hipMemsetAsync(logv, 0, 2 * Bn * L * 4, stream);
    hipMemsetAsync(out, 0, (size_t)out_size * 4, stream);

    // GEMM1: s1W = s1 @ W
    gemm_nt<<<dim3((int)(D / BN), (int)(Bn * L / BM), 1), 256, 0, stream>>>(
        s1b, WTb, (int)D, (int)D, (int)D, 0, 0,
        0, -1, s1W, (int)D, 0,
        nullptr, 0, 0, nullptr, 0, 0, nullptr, nullptr, 0);

    // GEMM3a: s1Wv(+T) = s1 @ Wv
    gemm_nt<<<dim3((int)(Aa / BN), (int)(Bn * L / BM), 1), 256, 0, stream>>>(
        s1b, WvTb, (int)D, (int)D, (int)D, 0, 0,
        2, -1, s1Wv, (int)Aa, 0,
        s1WvT, (int)L, L * Aa, nullptr, 0, 0, nullptr, nullptr, 0);

    // GEMM3b: s2Wq(+T) = s2 @ Wq
    gemm_nt<<<dim3((int)(Aa / BN), (int)(Bn * L / BM), 1), 256, 0, stream>>>(
        s2b, WqTb, (int)D, (int)D, (int)D, 0, 0,
        2, -1, s2Wq, (int)Aa, 0,
        s2WqT, (int)L, L * Aa, nullptr, 0, 0, nullptr, nullptr, 0);

    // GEMM2 (batched, XCD-clustered: 16 tiles/z): C = tanh(s1W @ s2^T) + C^T
    gemm_nt<<<dim3((int)(L / BN), (int)(L / BM), (int)Bn), 256, 0, stream>>>(
        s1W, s2b, (int)D, (int)D, (int)D, L * D, L * D,
        1, 4, Cb, (int)L, L * L,
        CTb, (int)L, L * L, nullptr, 0, 0, nullptr, nullptr, 0);

    // GEMM4a (XCD-clustered: 8 tiles/z): logits_v += rowsum tanh(s1Wv + C @ s2Wq)*whv
    gemm_nt<<<dim3((int)(Aa / BN), (int)(L / BM), (int)Bn), 256, 0, stream>>>(
        Cb, s2WqT, (int)L, (int)L, (int)L, L * L, Aa * L,
        3, 3, nullptr, 0, 0, nullptr, 0, 0,
        s1Wv, (int)Aa, L * Aa, whv, logv, L);

    // GEMM4b (XCD-clustered): logits_q += rowsum tanh(s2Wq + C^T @ s1Wv)*whq
    gemm_nt<<<dim3((int)(Aa / BN), (int)(L / BM), (int)Bn), 256, 0, stream>>>(
        CTb, s1WvT, (int)L, (int)L, (int)L, L * L, Aa * L,
        3, 3, nullptr, 0, 0, nullptr, 0, 0,
        s2Wq, (int)Aa, L * Aa, whq, logq, L);

    softmax_gather<<<dim3((int)Bn, 2, 4), 512, 0, stream>>>(
        logv, logq, mask1, mask2, s1, s2, s1b, s2b, use_ded, out);
}

// Round 6
// 298.442 us; speedup vs baseline: 1.3942x; 1.1255x over previous
//
#include <hip/hip_runtime.h>

typedef _Float16 f16;
typedef _Float16 f16x8 __attribute__((ext_vector_type(8)));
typedef _Float16 f16x4 __attribute__((ext_vector_type(4)));
typedef float f32x4 __attribute__((ext_vector_type(4)));

#define BM 128
#define BN 128

__device__ __forceinline__ float fast_tanh(float x) {
    return 1.0f - 2.0f / (__expf(2.0f * x) + 1.0f);
}

// async 16B global->LDS: LDS dest = wave-uniform base + lane*16
__device__ __forceinline__ void ld16(const void* g, void* l) {
    __builtin_amdgcn_global_load_lds(
        (const __attribute__((address_space(1))) void*)g,
        (__attribute__((address_space(3))) void*)l, 16, 0, 0);
}

// ---------------- prep: converts + weight transposes + zero-init ----------
// blocks [0,32768): s1/s2 f32->f16 (float4 per thread)
// blocks [32768,34816): W/Wv/Wq transpose+convert
// blocks [34816,34944): zero logv/logq/out
__global__ __launch_bounds__(256) void prep(
    const float* __restrict__ s1, const float* __restrict__ s2,
    f16* __restrict__ s1b, f16* __restrict__ s2b,
    const float* __restrict__ W, const float* __restrict__ Wv,
    const float* __restrict__ Wq,
    f16* __restrict__ WTb, f16* __restrict__ WvTb, f16* __restrict__ WqTb,
    float* __restrict__ logv, float* __restrict__ out)
{
    int bid = blockIdx.x, tid = threadIdx.x;
    if (bid < 32768) {
        int g = bid * 256 + tid;                  // [0, 8388608)
        const int F = 4194304;                    // float4 per tensor
        const float* src = (g < F) ? s1 : s2;
        f16* dst = (g < F) ? s1b : s2b;
        int i = (g < F) ? g : g - F;
        float4 v = ((const float4*)src)[i];
        f16x4 h = {(f16)v.x, (f16)v.y, (f16)v.z, (f16)v.w};
        *(f16x4*)(dst + 4L * i) = h;
    } else if (bid < 34816) {
        int t2 = (bid - 32768) * 256 + tid;       // [0, 524288)
        if (t2 < 262144) {                        // W [512x512] -> WT
            int c = t2 >> 9, r = t2 & 511;
            WTb[t2] = (f16)W[r * 512 + c];
        } else if (t2 < 393216) {                 // Wv [512x256] -> WvT
            int i = t2 - 262144;
            int c = i >> 9, r = i & 511;
            WvTb[i] = (f16)Wv[r * 256 + c];
        } else {                                  // Wq [512x256] -> WqT
            int i = t2 - 393216;
            int c = i >> 9, r = i & 511;
            WqTb[i] = (f16)Wq[r * 256 + c];
        }
    } else {
        int t3 = (bid - 34816) * 256 + tid;       // [0, 32768) float4
        float4 z = {0.f, 0.f, 0.f, 0.f};
        if (t3 < 16384) ((float4*)logv)[t3] = z;  // logv+logq (65536 floats)
        else ((float4*)out)[t3 - 16384] = z;      // out (65536 floats)
    }
}

// ---------------- job-table GEMM ------------------------------------------
// NT GEMM: D[m][n] = sum_k A[m][k]*B[n][k], fp16 in, f32 accum, K%32==0.
// Double-buffered LDS K-loop, raw s_barrier + vmcnt(4) prefetch wait.
// swz >= 0: z-batched XCD cluster (tiles/z = 1<<swz share bid%8).
// swz == -2: single-batch XCD cluster (gy=256): by = xcd*32+v -> each A-panel
//            fetched by exactly one XCD.
// modes: 0 = store f16 C; 1 = tanh -> C + staged C^T; 2 = C + staged C^T;
//        3 = logits epilogue.
struct Job {
    const f16* A; const f16* B;
    f16* Cout; f16* CTout;
    const f16* Sadd;
    const float* wvec;
    float* logits;
    long sA, sB, sC, sCT, sS, sL;
    int lda, ldb, ldc, ldct, ldsa;
    int mode, swz, gxl, K;
};
struct JobPack { Job j[3]; int end0, end1; };

__global__ __launch_bounds__(256, 3) void gemm_multi(JobPack jp) {
    int bid = blockIdx.x;
    int ji = (bid < jp.end0) ? 0 : ((bid < jp.end1) ? 1 : 2);
    const Job J = jp.j[ji];
    int local = bid - ((ji == 0) ? 0 : ((ji == 1) ? jp.end0 : jp.end1));

    int bx, by, bz;
    if (J.swz >= 0) {
        int tg = local >> 3;
        bz = (local & 7) + 8 * (tg >> J.swz);
        int t = tg & ((1 << J.swz) - 1);
        bx = t & ((1 << J.gxl) - 1);
        by = t >> J.gxl;
    } else {  // -2: single batch, gy=256
        bz = 0;
        int x = local & 7, u = local >> 3;
        bx = u >> 5;
        by = (x << 5) | (u & 31);
    }

    const f16* Ab = J.A + (long)bz * J.sA;
    const f16* Bb = J.B + (long)bz * J.sB;
    int m0 = by * BM;
    int n0 = bx * BN;
    int tid = threadIdx.x;
    int wave = tid >> 6, lane = tid & 63;
    int quad = lane >> 4, l16 = lane & 15;
    int wm = (wave >> 1) * 64, wn = (wave & 1) * 64;

    __shared__ __align__(16) char smem[32768];  // 2 x (As 8K + Bs 8K); T overlays
    f16* T = (f16*)smem;

    f32x4 zero = {0.f, 0.f, 0.f, 0.f};
    f32x4 acc[4][4];
#pragma unroll
    for (int i = 0; i < 4; i++)
#pragma unroll
        for (int j = 0; j < 4; j++) acc[i][j] = zero;

    int lda = J.lda, ldb = J.ldb;
    auto stage = [&](int buf, int k0) {
        f16* As = (f16*)(smem + buf * 16384);
        f16* Bs = (f16*)(smem + buf * 16384 + 8192);
#pragma unroll
        for (int j = 0; j < 2; j++) {
            int rbase = wave * 32 + j * 16;
            int r = rbase + (lane >> 2);
            int sw = ((lane & 3) ^ ((r >> 1) & 3)) << 3;
            ld16(Ab + (long)(m0 + r) * lda + k0 + sw, As + rbase * 32);
            ld16(Bb + (long)(n0 + r) * ldb + k0 + sw, Bs + rbase * 32);
        }
    };

    const int NK = J.K >> 5;
    stage(0, 0);
    for (int ki = 0; ki < NK; ki++) {
        int cur = ki & 1;
        __builtin_amdgcn_s_barrier();           // buf[1-cur] readers done
        asm volatile("" ::: "memory");
        if (ki + 1 < NK) {
            stage(1 - cur, (ki + 1) << 5);
            __builtin_amdgcn_s_waitcnt(0xF74);  // vmcnt(4): tile-ki DMAs done
        } else {
            __builtin_amdgcn_s_waitcnt(0xF70);  // vmcnt(0)
        }
        __builtin_amdgcn_s_barrier();           // tile-ki visible to all
        asm volatile("" ::: "memory");

        const f16* As = (const f16*)(smem + cur * 16384);
        const f16* Bs = (const f16*)(smem + cur * 16384 + 8192);
        f16x8 af[4], bfr[4];
#pragma unroll
        for (int mt = 0; mt < 4; mt++) {
            int row = wm + mt * 16 + l16;
            af[mt] = *(const f16x8*)(As + row * 32 + ((quad ^ ((row >> 1) & 3)) << 3));
        }
#pragma unroll
        for (int nt = 0; nt < 4; nt++) {
            int row = wn + nt * 16 + l16;
            bfr[nt] = *(const f16x8*)(Bs + row * 32 + ((quad ^ ((row >> 1) & 3)) << 3));
        }
#pragma unroll
        for (int mt = 0; mt < 4; mt++)
#pragma unroll
            for (int nt = 0; nt < 4; nt++)
                acc[mt][nt] = __builtin_amdgcn_mfma_f32_16x16x32_f16(af[mt], bfr[nt], acc[mt][nt], 0, 0, 0);
        asm volatile("" ::: "memory");
    }

    int gmb = m0 + wm;
    int gnb = n0 + wn;

    if (J.mode == 3) {
        const f16* Sb = J.Sadd + (long)bz * J.sS;
        float* lg = J.logits + (long)bz * J.sL;
#pragma unroll
        for (int mt = 0; mt < 4; mt++) {
            int rowb = gmb + mt * 16 + quad * 4;
            float part[4] = {0.f, 0.f, 0.f, 0.f};
#pragma unroll
            for (int nt = 0; nt < 4; nt++) {
                int col = gnb + nt * 16 + l16;
                float w = J.wvec[col];
#pragma unroll
                for (int r = 0; r < 4; r++) {
                    float s = (float)Sb[(long)(rowb + r) * J.ldsa + col];
                    part[r] += fast_tanh(s + acc[mt][nt][r]) * w;
                }
            }
#pragma unroll
            for (int off = 1; off < 16; off <<= 1) {
#pragma unroll
                for (int r = 0; r < 4; r++) part[r] += __shfl_xor(part[r], off);
            }
            if (l16 == 0) {
#pragma unroll
                for (int r = 0; r < 4; r++) atomicAdd(&lg[rowb + r], part[r]);
            }
        }
        return;
    }

    // convert (and tanh for mode 1) ONCE into f16 regs; reuse for both stores
    f16x4 hreg[4][4];
#pragma unroll
    for (int mt = 0; mt < 4; mt++)
#pragma unroll
        for (int nt = 0; nt < 4; nt++) {
            float v0 = acc[mt][nt][0], v1 = acc[mt][nt][1];
            float v2 = acc[mt][nt][2], v3 = acc[mt][nt][3];
            if (J.mode == 1) {
                v0 = fast_tanh(v0); v1 = fast_tanh(v1);
                v2 = fast_tanh(v2); v3 = fast_tanh(v3);
            }
            f16x4 hv = {(f16)v0, (f16)v1, (f16)v2, (f16)v3};
            hreg[mt][nt] = hv;
        }

    f16* Cb = J.Cout + (long)bz * J.sC;
#pragma unroll
    for (int mt = 0; mt < 4; mt++) {
        int rowb = gmb + mt * 16 + quad * 4;
#pragma unroll
        for (int nt = 0; nt < 4; nt++) {
            int col = gnb + nt * 16 + l16;
#pragma unroll
            for (int r = 0; r < 4; r++)
                Cb[(long)(rowb + r) * J.ldc + col] = hreg[mt][nt][r];
        }
    }

    if (J.mode == 1 || J.mode == 2) {
        // staged transpose through LDS -> coalesced CT stores
        long bb = (J.mode == 2) ? (m0 >> 9) : bz;  // mode2: M-batched; mode1: z
        int lr0  = (J.mode == 2) ? (m0 & 511) : m0;
        f16* CTb = J.CTout + bb * J.sCT;
#pragma unroll
        for (int h = 0; h < 2; h++) {
            __syncthreads();
            if ((wave & 1) == h) {
#pragma unroll
                for (int mt = 0; mt < 4; mt++) {
                    int rloc = wm + mt * 16 + quad * 4;
#pragma unroll
                    for (int nt = 0; nt < 4; nt++) {
                        int cloc = nt * 16 + l16;
                        *(f16x4*)(T + cloc * 136 + rloc) = hreg[mt][nt];
                    }
                }
            }
            __syncthreads();
#pragma unroll
            for (int i = 0; i < 4; i++) {
                int id = tid + i * 256;
                int c = id >> 4, r8 = (id & 15) * 8;
                f16x8 v = *(const f16x8*)(T + c * 136 + r8);
                *(f16x8*)(CTb + (long)(n0 + h * 64 + c) * J.ldct + lr0 + r8) = v;
            }
        }
    }
}

__device__ __forceinline__ float block_reduce(float v, float* red, int tid, bool is_max) {
#pragma unroll
    for (int off = 32; off >= 1; off >>= 1) {
        float o = __shfl_xor(v, off);
        v = is_max ? fmaxf(v, o) : (v + o);
    }
    if ((tid & 63) == 0) red[tid >> 6] = v;
    __syncthreads();
    float t = red[0];
#pragma unroll
    for (int i = 1; i < 8; i++) t = is_max ? fmaxf(t, red[i]) : (t + red[i]);
    __syncthreads();
    return t;
}

// grid (B, 2, 8): masked softmax over 512 logits (recomputed per z-slice),
// partial gather over 64 l's -> atomicAdd into out.
__global__ __launch_bounds__(512) void softmax_gather(
    const float* __restrict__ logits_v, const float* __restrict__ logits_q,
    const int* __restrict__ mask1, const int* __restrict__ mask2,
    const float* __restrict__ s1f, const float* __restrict__ s2f,
    const f16* __restrict__ s1h, const f16* __restrict__ s2h, int use_h,
    float* __restrict__ out)
{
    int b = blockIdx.x;
    int which = blockIdx.y;
    int zp = blockIdx.z;
    const float* lg = (which ? logits_q : logits_v) + (long)b * 512;
    const int*   mk = (which ? mask2 : mask1) + (long)b * 512;
    float* o = out + (long)which * 64 * 512 + (long)b * 512;

    int tid = threadIdx.x;
    __shared__ float p[512];
    __shared__ float red[8];

    float m = (float)mk[tid];
    float x = lg[tid] * m;
    float mx = block_reduce(x, red, tid, true);
    float e = __expf(x - mx);
    float S1 = block_reduce(e, red, tid, false);
    float r = (e / S1) * m;
    float S2 = block_reduce(r, red, tid, false);
    p[tid] = r / (S2 + 1e-13f);
    __syncthreads();

    float acc = 0.f;
    int l0 = zp * 64;
    if (use_h) {
        const f16* S = (which ? s2h : s1h) + (long)b * 512 * 512;
#pragma unroll 8
        for (int l = l0; l < l0 + 64; l++) acc += p[l] * (float)S[(long)l * 512 + tid];
    } else {
        const float* S = (which ? s2f : s1f) + (long)b * 512 * 512;
#pragma unroll 8
        for (int l = l0; l < l0 + 64; l++) acc += p[l] * S[(long)l * 512 + tid];
    }
    atomicAdd(&o[tid], acc);
}

extern "C" void kernel_launch(void* const* d_in, const int* in_sizes, int n_in,
                              void* d_out, int out_size, void* d_ws, size_t ws_size,
                              hipStream_t stream) {
    const float* s1  = (const float*)d_in[0];
    const float* s2  = (const float*)d_in[1];
    const int* mask1 = (const int*)d_in[2];
    const int* mask2 = (const int*)d_in[3];
    const float* W   = (const float*)d_in[4];
    const float* Wv  = (const float*)d_in[5];
    const float* Wq  = (const float*)d_in[6];
    const float* whv = (const float*)d_in[7];
    const float* whq = (const float*)d_in[8];
    float* out = (float*)d_out;

    const long Bn = 64, L = 512, D = 512, Aa = 256;
    char* ws = (char*)d_ws;
    size_t off = 0;
    auto alloc = [&](size_t bytes) -> char* {
        char* p = ws + off;
        off += (bytes + 255) & ~(size_t)255;
        return p;
    };
    f16* s1b   = (f16*)alloc(Bn * L * D * 2);
    f16* s2b   = (f16*)alloc(Bn * L * D * 2);
    f16* s1W   = (f16*)alloc(Bn * L * D * 2);
    f16* Cb    = (f16*)alloc(Bn * L * L * 2);
    f16* s1Wv  = (f16*)alloc(Bn * L * Aa * 2);
    f16* s1WvT = (f16*)alloc(Bn * L * Aa * 2);
    f16* s2Wq  = (f16*)alloc(Bn * L * Aa * 2);
    f16* s2WqT = (f16*)alloc(Bn * L * Aa * 2);
    f16* WTb   = (f16*)alloc(D * D * 2);
    f16* WvTb  = (f16*)alloc(D * Aa * 2);
    f16* WqTb  = (f16*)alloc(D * Aa * 2);
    float* logv = (float*)alloc(2 * Bn * L * 4);
    float* logq = logv + Bn * L;
    size_t base_off = off;
    f16* CTded = (f16*)alloc(Bn * L * L * 2);  // optional dedicated CT
    if (ws_size < base_off) return;
    int use_ded = (ws_size >= off) ? 1 : 0;
    f16* CTb = use_ded ? CTded : s1b;  // fallback: alias s1b (dead as f16 input)

    // 1) prep: converts + transposes + zero logits/out
    prep<<<dim3(34944), 256, 0, stream>>>(s1, s2, s1b, s2b, W, Wv, Wq,
                                          WTb, WvTb, WqTb, logv, out);

    Job z0{};  // zeroed spare

    // 2) merged GEMM1 + GEMM3a + GEMM3b (2048 blocks)
    {
        JobPack p{};
        Job& a = p.j[0];  // GEMM1: s1W = s1 @ W  (gx=4, gy=256)
        a.A = s1b; a.B = WTb; a.Cout = s1W;
        a.lda = 512; a.ldb = 512; a.ldc = 512; a.K = 512;
        a.mode = 0; a.swz = -2; a.gxl = 2;
        Job& b = p.j[1];  // GEMM3a: s1Wv(+T) = s1 @ Wv (gx=2, gy=256)
        b.A = s1b; b.B = WvTb; b.Cout = s1Wv; b.CTout = s1WvT;
        b.lda = 512; b.ldb = 512; b.ldc = 256; b.ldct = 512; b.sCT = L * Aa;
        b.K = 512; b.mode = 2; b.swz = -2; b.gxl = 1;
        Job& c = p.j[2];  // GEMM3b: s2Wq(+T) = s2 @ Wq
        c.A = s2b; c.B = WqTb; c.Cout = s2Wq; c.CTout = s2WqT;
        c.lda = 512; c.ldb = 512; c.ldc = 256; c.ldct = 512; c.sCT = L * Aa;
        c.K = 512; c.mode = 2; c.swz = -2; c.gxl = 1;
        p.end0 = 1024; p.end1 = 1536;
        gemm_multi<<<dim3(2048), 256, 0, stream>>>(p);
    }

    // 3) GEMM2 (batched, XCD-clustered 16 tiles/z): C = tanh(s1W @ s2^T) + C^T
    {
        JobPack p{};
        Job& a = p.j[0];
        a.A = s1W; a.B = s2b; a.Cout = Cb; a.CTout = CTb;
        a.lda = 512; a.ldb = 512; a.ldc = 512; a.ldct = 512;
        a.sA = L * D; a.sB = L * D; a.sC = L * L; a.sCT = L * L;
        a.K = 512; a.mode = 1; a.swz = 4; a.gxl = 2;
        p.j[1] = z0; p.j[2] = z0;
        p.end0 = 1024; p.end1 = 1024;
        gemm_multi<<<dim3(1024), 256, 0, stream>>>(p);
    }

    // 4) merged GEMM4a + GEMM4b (1024 blocks, XCD-clustered 8 tiles/z)
    {
        JobPack p{};
        Job& a = p.j[0];  // logits_v += rowsum tanh(s1Wv + C @ s2Wq) * whv
        a.A = Cb; a.B = s2WqT; a.Sadd = s1Wv; a.wvec = whv; a.logits = logv;
        a.lda = 512; a.ldb = 512; a.ldsa = 256;
        a.sA = L * L; a.sB = Aa * L; a.sS = L * Aa; a.sL = 512;
        a.K = 512; a.mode = 3; a.swz = 3; a.gxl = 1;
        Job& b = p.j[1];  // logits_q += rowsum tanh(s2Wq + C^T @ s1Wv) * whq
        b.A = CTb; b.B = s1WvT; b.Sadd = s2Wq; b.wvec = whq; b.logits = logq;
        b.lda = 512; b.ldb = 512; b.ldsa = 256;
        b.sA = L * L; b.sB = Aa * L; b.sS = L * Aa; b.sL = 512;
        b.K = 512; b.mode = 3; b.swz = 3; b.gxl = 1;
        p.j[2] = z0;
        p.end0 = 512; p.end1 = 1024;
        gemm_multi<<<dim3(1024), 256, 0, stream>>>(p);
    }

    // 5) masked softmax + weighted gather
    softmax_gather<<<dim3((int)Bn, 2, 8), 512, 0, stream>>>(
        logv, logq, mask1, mask2, s1, s2, s1b, s2b, use_ded, out);
}